// Round 7
// baseline (97.274 us; speedup 1.0000x reference)
//
#include <hip/hip_runtime.h>

// ChamferLoss: x,y (16,4096,3) f32 -> scalar.
// R15: bisection + perf. R13 and R14 failed IDENTICALLY (~0.084) despite
// independent transports -> bug is in a composition interface between
// R12's MFMA math and the R0-R11 topology (js full-scan loop / block-local
// epilogue). R15 uses ONLY R12-verified machinery, made dir-symmetric:
// grid 4096 = dir(2) x b(16) x js(4) x ic(32); each block is R12's dir1
// path verbatim (one js slice, no js loop, atomicMin transport, final
// kernel). Only novelty: dir-swap pointer select (verified by R0-R11).
// Drops all dir2 code: LDS 48.5->32.6 KB (4 blocks/CU), atomics
// 2.36M/32-way -> 524K/4-way.
// Target main 8-14us, dur_us 58-68 (incl. fixed 40us ws-fill tax).

#define NP 4096
#define NB 16
#define BLK 256
#define NBLOCKS 4096            // dir(2) x b(16) x js(4) x ic(32)

typedef float f32x16 __attribute__((ext_vector_type(16)));
typedef short s16x8 __attribute__((ext_vector_type(8)));

__device__ __forceinline__ float fmin3f(float a, float b, float c) {
  float d;
  asm("v_min3_f32 %0, %1, %2, %3" : "=v"(d) : "v"(a), "v"(b), "v"(c));
  return d;
}

__device__ __forceinline__ unsigned short f2bf(float v) {
  unsigned u = __float_as_uint(v);
  u += 0x7FFFu + ((u >> 16) & 1u);        // RNE to bf16
  return (unsigned short)(u >> 16);
}
__device__ __forceinline__ float bf2f(unsigned short s) {
  return __uint_as_float(((unsigned)s) << 16);
}

__global__ __launch_bounds__(256) void chamfer_init(unsigned* __restrict__ ws,
                                                    float* __restrict__ out) {
  const int i = blockIdx.x * 256 + threadIdx.x;   // grid 512 -> 131072
  ws[i] = 0x7F800000u;                            // +inf
  if (i == 0) out[0] = 0.0f;
}

// K-slot layout (A = queries as rows, B = db points as cols), R12-verified:
//  k0-2 : sh(x,y,z)*dh(x,y,z)   (s = -2*q, hi)    k9,10 : 1*d2h, 1*d2l
//  k3-5 : sh*dl                                   k11,12: q2h*1, q2l*1
//  k6-8 : sl*dh                                   k13-15: 0
// A-frag lane l: row=l%32, k=(l/32)*8+i ; B-frag: col=l%32, k=(l/32)*8+i.
// C/D: col=lane&31, row=(reg&3)+8*(reg>>2)+4*(lane>>5).

__global__ __launch_bounds__(BLK) void chamfer_main(
    const float* __restrict__ x, const float* __restrict__ y,
    unsigned* __restrict__ ws) {
  const int bid = blockIdx.x;
  const int dir = bid >> 11;
  const int b   = (bid >> 7) & 15;
  const int js  = (bid >> 5) & 3;
  const int ic  = bid & 31;

  // dir 0: queries = x rows, db = y cols (reference min1)
  // dir 1: queries = y rows, db = x cols (reference min2)
  const float* q_base = (dir == 0 ? x : y) + (size_t)b * NP * 3;
  const float* d_base = (dir == 0 ? y : x) + ((size_t)b * NP + js * 1024) * 3;

  __shared__ s16x8 yfrag[2048];       // 32 KB: this block's 1024-pt db slice
  __shared__ float m1s[128];

  const int tid  = threadIdx.x;
  const int lane = tid & 63;
  const int w    = tid >> 6;
  const int row  = lane & 31;
  const int hf   = lane >> 5;
  const short ONE = (short)0x3F80;    // bf16(1.0)

  // ---- A-frag: this lane's query point (R12-verbatim) ----
  const int qi = ic * 128 + w * 32 + row;
  const float qx = q_base[qi * 3 + 0];
  const float qy = q_base[qi * 3 + 1];
  const float qz = q_base[qi * 3 + 2];
  const float sx = -2.0f * qx, sy = -2.0f * qy, sz = -2.0f * qz;
  const unsigned short shx = f2bf(sx), shy = f2bf(sy), shz = f2bf(sz);
  const unsigned short slx = f2bf(sx - bf2f(shx));
  const unsigned short sly = f2bf(sy - bf2f(shy));
  const unsigned short slz = f2bf(sz - bf2f(shz));
  const float q2 = fmaf(qx, qx, fmaf(qy, qy, qz * qz));
  const unsigned short q2h = f2bf(q2);
  const unsigned short q2l = f2bf(q2 - bf2f(q2h));
  const s16x8 a0 = {(short)shx, (short)shy, (short)shz,
                    (short)shx, (short)shy, (short)shz,
                    (short)slx, (short)sly};
  const s16x8 a1 = {(short)slz, ONE, ONE, (short)q2h, (short)q2l, 0, 0, 0};
  const s16x8 afr = hf ? a1 : a0;

  // ---- stage this js slice (1024 pts) as prepacked B-frags (R12-verbatim) ----
#pragma unroll
  for (int k = 0; k < 4; ++k) {
    const int j = tid + k * 256;
    const float y0 = d_base[j * 3 + 0];
    const float y1 = d_base[j * 3 + 1];
    const float y2 = d_base[j * 3 + 2];
    const unsigned short dh0 = f2bf(y0), dh1 = f2bf(y1), dh2 = f2bf(y2);
    const unsigned short dl0 = f2bf(y0 - bf2f(dh0));
    const unsigned short dl1 = f2bf(y1 - bf2f(dh1));
    const unsigned short dl2 = f2bf(y2 - bf2f(dh2));
    const float d2 = fmaf(y0, y0, fmaf(y1, y1, y2 * y2));
    const unsigned short d2h = f2bf(d2);
    const unsigned short d2l = f2bf(d2 - bf2f(d2h));
    const s16x8 h0 = {(short)dh0, (short)dh1, (short)dh2,
                      (short)dl0, (short)dl1, (short)dl2,
                      (short)dh0, (short)dh1};
    const s16x8 h1 = {(short)dh2, (short)d2h, (short)d2l, ONE, ONE, 0, 0, 0};
    const int jt = j >> 5, jc = j & 31;
    yfrag[jt * 64 + jc]      = h0;    // read by lanes 0..31
    yfrag[jt * 64 + 32 + jc] = h1;    // read by lanes 32..63
  }
  __syncthreads();

  // ---- MFMA inner loop (R12-verbatim, dir2 code dropped) ----
  float m1[16];
#pragma unroll
  for (int r = 0; r < 16; ++r) m1[r] = 3.4e38f;
  const f32x16 zc = {};
  const s16x8* base = &yfrag[0] + lane;     // ds addr = lane*16 + jt*1024 (imm)

#pragma unroll
  for (int jt = 0; jt < 32; jt += 2) {
    const s16x8 b0 = base[jt * 64];
    const s16x8 b1 = base[(jt + 1) * 64];
    const f32x16 d0 = __builtin_amdgcn_mfma_f32_32x32x16_bf16(afr, b0, zc, 0, 0, 0);
    const f32x16 d1 = __builtin_amdgcn_mfma_f32_32x32x16_bf16(afr, b1, zc, 0, 0, 0);
#pragma unroll
    for (int r = 0; r < 16; ++r) m1[r] = fmin3f(d0[r], d1[r], m1[r]);
  }

  // ---- min across the 32 cols (R12-verbatim) ----
#pragma unroll
  for (int s = 1; s <= 16; s <<= 1) {
#pragma unroll
    for (int r = 0; r < 16; ++r) m1[r] = fminf(m1[r], __shfl_xor(m1[r], s));
  }

  // ---- park row mins in m1s (R12-verbatim) ----
  if ((lane & 31) == 0) {
#pragma unroll
    for (int r = 0; r < 16; ++r) {
      const int rw = (r & 3) + 8 * (r >> 2) + 4 * hf;
      m1s[w * 32 + rw] = m1[r];
    }
  }
  __syncthreads();

  // ---- cross-block combine via atomicMin on uint-cast floats (R12-verbatim) ----
  if (tid < 128) {
    const float v = fmaxf(m1s[tid], 0.0f);
    atomicMin(&ws[(size_t)dir * 65536 + (size_t)b * NP + ic * 128 + tid],
              __float_as_uint(v));
  }
}

__global__ __launch_bounds__(256) void chamfer_final(
    const unsigned* __restrict__ ws, float* __restrict__ out) {
  const int i = blockIdx.x * 256 + threadIdx.x;   // grid 512 -> 131072
  float s = sqrtf(__uint_as_float(ws[i]) + 1e-6f);
#pragma unroll
  for (int off = 32; off > 0; off >>= 1) s += __shfl_down(s, off);
  __shared__ float wsum[4];
  if ((threadIdx.x & 63) == 0) wsum[threadIdx.x >> 6] = s;
  __syncthreads();
  if (threadIdx.x == 0)
    atomicAdd(out, (wsum[0] + wsum[1] + wsum[2] + wsum[3]) * (1.0f / 65536.0f));
}

extern "C" void kernel_launch(void* const* d_in, const int* in_sizes, int n_in,
                              void* d_out, int out_size, void* d_ws, size_t ws_size,
                              hipStream_t stream) {
  const float* x = (const float*)d_in[0];
  const float* y = (const float*)d_in[1];
  float* out = (float*)d_out;
  unsigned* ws = (unsigned*)d_ws;   // uses 512 KB

  chamfer_init<<<512, 256, 0, stream>>>(ws, out);
  chamfer_main<<<NBLOCKS, BLK, 0, stream>>>(x, y, ws);
  chamfer_final<<<512, 256, 0, stream>>>(ws, out);
}